// Round 5
// baseline (283.347 us; speedup 1.0000x reference)
//
#include <hip/hip_runtime.h>
#include <hip/hip_bf16.h>
#include <stdint.h>

#define Bn   8
#define Cn   64
#define Nn   40962
#define Kn   7
#define OUTn 64
// flattened K = 7 neighbors x 64 ch = 448 = 7 stages x (2 MFMA k-chunks of 32)

typedef __bf16 bf16x8 __attribute__((ext_vector_type(8)));
typedef float  f32x4  __attribute__((ext_vector_type(4)));
typedef unsigned int u32;
typedef const __attribute__((address_space(1))) u32* gas1p;
typedef __attribute__((address_space(3))) u32* sas3p;

__device__ __forceinline__ void dma16(const void* g, void* s) {
    // global -> LDS direct DMA, 16 B/lane; dest = uniform base + lane*16
    __builtin_amdgcn_global_load_lds((gas1p)g, (sas3p)s, 16, 0, 0);
}
#define FENCE()      asm volatile("" ::: "memory")
#define WAIT_VM16()  asm volatile("s_waitcnt vmcnt(16)" ::: "memory")
#define WAIT_VM0()   asm volatile("s_waitcnt vmcnt(0)" ::: "memory")
#define WAIT_LGKM0() asm volatile("s_waitcnt lgkmcnt(0)" ::: "memory")

// ---------------------------------------------------------------------------
// Convert W [64,448] f32 -> bf16 once per call.
// ---------------------------------------------------------------------------
__global__ __launch_bounds__(256) void convw_kernel(
    const float* __restrict__ W, __bf16* __restrict__ Wb)
{
    int i = blockIdx.x * 256 + threadIdx.x;
    if (i < OUTn * Kn * Cn) Wb[i] = (__bf16)W[i];
}

// ---------------------------------------------------------------------------
// Pass 1: x [B][C][N] f32  ->  xT [N][B][C] bf16 (each vertex = 1 KB row).
// Two passes of 256 (b*64+c)-rows through a 64n x 264 LDS tile.
// Output side: 512-B contiguous stores per wave-instruction.
// ---------------------------------------------------------------------------
__global__ __launch_bounds__(256) void transpose_kernel(
    const float* __restrict__ x, __bf16* __restrict__ xT)
{
    __shared__ __bf16 tile[64][264];   // stride 264 elem = 528 B: 16B-aligned rows
    const int t    = threadIdx.x;
    const int lane = t & 63;
    const int w    = t >> 6;
    const int n0   = blockIdx.x * 64;
    const int n    = n0 + lane;
    const bool okn = n < Nn;

#pragma unroll
    for (int p = 0; p < 2; ++p) {
        if (p) __syncthreads();
        if (okn) {
#pragma unroll
            for (int i = 0; i < 64; ++i) {
                int rl = w * 64 + i;                 // local row 0..255
                int rg = p * 256 + rl;               // global row = b*64 + c
                tile[lane][rl] = (__bf16)x[(size_t)rg * Nn + n];
            }
        }
        __syncthreads();
#pragma unroll
        for (int i = 0; i < 8; ++i) {
            int q  = i * 256 + t;
            int nl = q >> 5;                         // 0..63
            int ch = q & 31;                         // 16-B chunk in 512-B half-row
            if (n0 + nl < Nn) {
                bf16x8 v = *(const bf16x8*)&tile[nl][ch * 8];
                *(bf16x8*)((char*)xT + (size_t)(n0 + nl) * 1024 + p * 512 + ch * 16) = v;
            }
        }
    }
}

// ---------------------------------------------------------------------------
// Pass 2: gather-GEMM, per-wave DMA-pipelined, barrier-free K-loop.
//   Wave tile: 8 vertices x 8 batches x 64 outputs.
//   MFMA 16x16x32: A = W (m=o), B = gathered xT (col = v2*8 + b).
//   Per stage kn: 8x dma16 groups (1 KB per vertex, all 8 batches),
//   double-buffered 8 KB LDS per wave; W frags double-buffered in VGPRs.
//   vmcnt ledger: each stage issues W(8)+D(8)=16; wait vmcnt(16) at stage top
//   retires exactly group kn (kn=6: vmcnt(0)). asm fences pin issue order.
// ---------------------------------------------------------------------------
__global__ __launch_bounds__(256) void gconv_kernel(
    const __bf16* __restrict__ xT,    // [N][B][C] bf16
    const int*    __restrict__ nbr,   // [N*7] int32
    const __bf16* __restrict__ Wb,    // [64][448] bf16
    const float*  __restrict__ bias,  // [64] f32
    float*        __restrict__ out)   // [B][64][N] f32
{
    __shared__ char stg[4][2][8192];  // per-wave double buffer
    const int tid  = threadIdx.x;
    const int w    = tid >> 6;
    const int l    = tid & 63;
    const int col  = l & 15;
    const int quad = l >> 4;
    const int wb   = blockIdx.x * 32 + w * 8;     // wave's vertex base

    // 56 neighbor indices for this wave, lane-parallel, clamped.
    int nadr = wb * 7 + l;
    nadr = nadr < Nn * Kn ? nadr : Nn * Kn - 1;
    int myidx = nbr[nadr];
    myidx = myidx < 0 ? 0 : (myidx >= Nn ? Nn - 1 : myidx);

    const char* xb = (const char*)xT;
    // DMA source swizzle: lane l fetches (b = l&7, chunk = l>>3) of the 1-KB row
    // so LDS chunk (cidx*8 + b) holds (b, cidx) -> conflict-free ds_read_b128.
    const int srcoff = (l & 7) * 128 + (l >> 3) * 16;

    // W frag byte offset: o*896 + kn*128 + kc2*64 + quad*16, o = s*16+col
    const char* wbase = (const char*)Wb + (size_t)col * 896 + quad * 16;

    bf16x8 Wreg[2][8];
    f32x4 acc[4][4];
#pragma unroll
    for (int s = 0; s < 4; ++s)
#pragma unroll
        for (int t4 = 0; t4 < 4; ++t4)
            acc[s][t4] = (f32x4){0.f, 0.f, 0.f, 0.f};

    char* buf0 = &stg[w][0][0];
    char* buf1 = &stg[w][1][0];

    auto issueW = [&](int kn, int slot) {
#pragma unroll
        for (int kc2 = 0; kc2 < 2; ++kc2)
#pragma unroll
            for (int s = 0; s < 4; ++s)
                Wreg[slot][kc2 * 4 + s] =
                    *(const bf16x8*)(wbase + (size_t)s * 16 * 896 + kn * 128 + kc2 * 64);
    };
    auto issueD = [&](int kn, char* buf) {
#pragma unroll
        for (int g = 0; g < 8; ++g) {
            int sidx = __builtin_amdgcn_readlane(myidx, g * 7 + kn);
            dma16(xb + (size_t)sidx * 1024 + srcoff, buf + g * 1024);
        }
    };

    // Prologue: issue groups 0 and 1 (order pinned: W then D per group).
    issueW(0, 0); FENCE();
    issueD(0, buf0); FENCE();
    issueW(1, 1); FENCE();
    issueD(1, buf1); FENCE();

#pragma unroll
    for (int kn = 0; kn < 7; ++kn) {
        if (kn < 6) { WAIT_VM16(); } else { WAIT_VM0(); }
        char* buf = (kn & 1) ? buf1 : buf0;
#pragma unroll
        for (int kc2 = 0; kc2 < 2; ++kc2) {
            bf16x8 bfrag[4];
#pragma unroll
            for (int t4 = 0; t4 < 4; ++t4) {
                int g = t4 * 2 + (col >> 3);
                bfrag[t4] = *(const bf16x8*)(buf + g * 1024
                                + ((kc2 * 4 + quad) * 8 + (col & 7)) * 16);
            }
#pragma unroll
            for (int s = 0; s < 4; ++s)
#pragma unroll
                for (int t4 = 0; t4 < 4; ++t4)
                    acc[s][t4] = __builtin_amdgcn_mfma_f32_16x16x32_bf16(
                        Wreg[kn & 1][kc2 * 4 + s], bfrag[t4], acc[s][t4], 0, 0, 0);
        }
        if (kn + 2 <= 6) {
            WAIT_LGKM0();                 // this wave's ds_reads of buf done
            issueW(kn + 2, kn & 1); FENCE();
            issueD(kn + 2, buf);    FENCE();
        }
    }

    // Epilogue: o = s*16 + quad*4 + r; col -> (v2 = col>>3, b = col&7);
    // n = wb + t4*2 + v2.
#pragma unroll
    for (int s = 0; s < 4; ++s)
#pragma unroll
        for (int r = 0; r < 4; ++r) {
            const int o = s * 16 + quad * 4 + r;
            const float bv = bias[o];
#pragma unroll
            for (int t4 = 0; t4 < 4; ++t4) {
                const int n = wb + t4 * 2 + (col >> 3);
                if (n < Nn)
                    out[((size_t)(col & 7) * OUTn + o) * Nn + n] = acc[s][t4][r] + bv;
            }
        }
}

// ---------------------------------------------------------------------------
// Fallback: no workspace needed. Pure f32. Slow but correct.
// ---------------------------------------------------------------------------
__global__ __launch_bounds__(256) void naive_kernel(
    const float* __restrict__ x,      // [B, C, N]
    const int*   __restrict__ nbr,
    const float* __restrict__ W,
    const float* __restrict__ bias,
    float*       __restrict__ out)
{
    __shared__ float xs[4][Kn * Cn];
    const int v = threadIdx.x >> 6;
    const int o = threadIdx.x & 63;
    const int b = blockIdx.y;
    const int n = blockIdx.x * 4 + v;
    const bool ok = n < Nn;
    const int nn = ok ? n : 0;

#pragma unroll
    for (int k = 0; k < Kn; ++k) {
        int id = nbr[nn * Kn + k];
        id = id < 0 ? 0 : (id >= Nn ? Nn - 1 : id);
        xs[v][k * Cn + o] = x[((size_t)b * Cn + o) * Nn + id];
    }
    __syncthreads();

    float acc = bias[o];
    for (int j = 0; j < Kn * Cn; ++j)
        acc += W[o * (Kn * Cn) + j] * xs[v][j];

    if (ok)
        out[((size_t)b * OUTn + o) * Nn + n] = acc;
}

extern "C" void kernel_launch(void* const* d_in, const int* in_sizes, int n_in,
                              void* d_out, int out_size, void* d_ws, size_t ws_size,
                              hipStream_t stream)
{
    const float* x    = (const float*)d_in[0];
    const int*   nbr  = (const int*)d_in[1];
    const float* W    = (const float*)d_in[2];
    const float* bias = (const float*)d_in[3];
    float*       out  = (float*)d_out;

    const size_t w_bytes  = (size_t)OUTn * Kn * Cn * sizeof(__bf16);      // 57344
    const size_t xt_bytes = (size_t)Nn * Bn * Cn * sizeof(__bf16);        // 41.9 MB

    if (ws_size >= w_bytes + xt_bytes) {
        __bf16* Wb = (__bf16*)d_ws;
        __bf16* xT = (__bf16*)((char*)d_ws + w_bytes);

        convw_kernel<<<(OUTn * Kn * Cn + 255) / 256, 256, 0, stream>>>(W, Wb);
        transpose_kernel<<<(Nn + 63) / 64, 256, 0, stream>>>(x, xT);
        gconv_kernel<<<(Nn + 31) / 32, 256, 0, stream>>>(xT, nbr, Wb, bias, out);
    } else {
        dim3 ngrid((Nn + 3) / 4, Bn);
        naive_kernel<<<ngrid, 256, 0, stream>>>(x, nbr, W, bias, out);
    }
}